// Round 7
// baseline (107.959 us; speedup 1.0000x reference)
//
#include <hip/hip_runtime.h>
#include <math.h>

// Problem geometry (fixed by the reference).
constexpr int Bc = 32, Fc = 513, Tc = 1600;
constexpr int FCH = 8;                  // f rows per strip
constexpr int SPB = 65;                 // strips/batch: 64 full + 1 single-row
constexpr int NWAVE = Bc * SPB * 2;     // 4160 (2 half-row waves per strip)
constexpr int WPB = 4, BLK = 256;       // 4 waves per block
constexpr int NBLK = NWAVE / WPB;       // 1040 blocks (exact)
constexpr long long NTOT = (long long)Bc * Fc * Tc;  // 26,265,600

typedef float f32x2 __attribute__((ext_vector_type(2)));

__device__ __forceinline__ f32x2 pk_fma(f32x2 a, f32x2 b, f32x2 c) {
    f32x2 d;
    asm("v_pk_fma_f32 %0, %1, %2, %3" : "=v"(d) : "v"(a), "v"(b), "v"(c));
    return d;
}
__device__ __forceinline__ f32x2 pk_add(f32x2 a, f32x2 b) {
    f32x2 d;
    asm("v_pk_add_f32 %0, %1, %2" : "=v"(d) : "v"(a), "v"(b));
    return d;
}
__device__ __forceinline__ f32x2 pk_mul(f32x2 a, f32x2 b) {
    f32x2 d;
    asm("v_pk_mul_f32 %0, %1, %2" : "=v"(d) : "v"(a), "v"(b));
    return d;
}

// Magic-add RNE round (|y| < 2^22 here). Matches rintf/jnp.round (absmax 0).
#define INV2PI 0.15915494309189535f
#define MAGICF 12582912.0f
#define N2PI  -6.283185307179586f

__device__ __forceinline__ void aw_acc(f32x2 x, float& sA, float& sB,
                                       f32x2 cinv, f32x2 cmag, f32x2 cnmag,
                                       f32x2 cn2pi) {
    f32x2 y = pk_fma(x, cinv, cmag);   // x*inv2pi + MAGIC
    f32x2 r = pk_add(y, cnmag);        // RNE(x*inv2pi)
    f32x2 w = pk_fma(r, cn2pi, x);     // x - 2pi*r
    sA += fabsf(w.x);                  // abs folds into v_add modifier
    sB += fabsf(w.y);
}

__global__ __launch_bounds__(BLK) void phase_main(
        const float* __restrict__ pr, const float* __restrict__ pg,
        float* __restrict__ partials,      // [3][NBLK]
        unsigned* __restrict__ counter,    // ticket, memset 0 per call
        float* __restrict__ out,           // 3 floats
        int use_atomic)
{
    const int lane = (int)threadIdx.x & 63;
    const int widx = (int)threadIdx.x >> 6;
    const int wv   = (int)blockIdx.x * WPB + widx;
    const int b    = wv / (SPB * 2);
    const int rem  = wv - b * (SPB * 2);
    const int k    = rem >> 1;
    const int h    = rem & 1;              // half-row: t in [h*800, h*800+800)
    const int f0   = k * FCH;
    const int len  = (k == SPB - 1) ? 1 : FCH;
    const bool edge = (lane == 0) && (h == 1);  // needs d[t=799] per row

    // Base pointers at (row f0, col h*800).
    const float* baseA = pr + ((size_t)b * Fc + (size_t)f0) * Tc + h * 800;
    const float* baseG = pg + ((size_t)b * Fc + (size_t)f0) * Tc + h * 800;

    const f32x2 cneg1 = {-1.0f, -1.0f};
    const f32x2 cinv  = {INV2PI, INV2PI};
    const f32x2 cmag  = {MAGICF, MAGICF};
    const f32x2 cnmag = {-MAGICF, -MAGICF};
    const f32x2 cn2pi = {N2PI, N2PI};
    const float mt = (lane < 8) ? 1.0f : 0.0f;  // tail chunk validity
    const f32x2 m2 = {mt, mt};

    float ipA = 0.f, ipB = 0.f, gdA = 0.f, gdB = 0.f, ptA = 0.f, ptB = 0.f;

    // 3-slot rotating row buffers (all indices literal after full unroll).
    // Chunks: c=0..2 full (t = h*800 + c*256 + lane*4), c=3 tail (lane<8,
    // t = h*800 + 768 + lane*4). EA/EG: col h*800-1 (=799), lane0 of h==1.
    float4 A[3][4], G[3][4];
    float  EA[3], EG[3];

    // Load row (f0-1+j), clamped to f0 when f0==0&&j==0, into slot s.
    auto loadj = [&](int s, int j) {
        int roff = j - 1;
        if (f0 == 0 && j == 0) roff = 0;
        const float* pa = baseA + (ptrdiff_t)roff * Tc;
        const float* pq = baseG + (ptrdiff_t)roff * Tc;
        #pragma unroll
        for (int c = 0; c < 3; ++c) {
            A[s][c] = *(const float4*)(pa + c * 256 + lane * 4);
            G[s][c] = *(const float4*)(pq + c * 256 + lane * 4);
        }
        if (lane < 8) {
            A[s][3] = *(const float4*)(pa + 768 + lane * 4);
            G[s][3] = *(const float4*)(pq + 768 + lane * 4);
        } else {
            A[s][3] = make_float4(0.f, 0.f, 0.f, 0.f);
            G[s][3] = make_float4(0.f, 0.f, 0.f, 0.f);
        }
        EA[s] = 0.f; EG[s] = 0.f;
        if (edge) { EA[s] = pa[-1]; EG[s] = pq[-1]; }
    };
    auto diff = [&](int s, float4 (&D)[4], float& dm) {
        #pragma unroll
        for (int c = 0; c < 4; ++c) {
            f32x2 x01 = {A[s][c].x, A[s][c].y}, x23 = {A[s][c].z, A[s][c].w};
            f32x2 y01 = {G[s][c].x, G[s][c].y}, y23 = {G[s][c].z, G[s][c].w};
            f32x2 d01 = pk_fma(y01, cneg1, x01);
            f32x2 d23 = pk_fma(y23, cneg1, x23);
            D[c] = make_float4(d01.x, d01.y, d23.x, d23.y);
        }
        dm = EA[s] - EG[s];
    };
    auto acc = [&](float4 (&D)[4], float dmv, float4 (&P)[4]) {
        #pragma unroll
        for (int c = 0; c < 4; ++c) {
            f32x2 d01 = {D[c].x, D[c].y}, d23 = {D[c].z, D[c].w};
            f32x2 p01 = {P[c].x, P[c].y}, p23 = {P[c].z, P[c].w};
            float up = __shfl_up(D[c].w, 1);
            float carry = (c == 0) ? ((h == 0) ? 0.f : dmv)
                                   : __shfl(D[c - 1].w, 63);
            float dm1 = (lane == 0) ? carry : up;
            f32x2 sh01 = {dm1, D[c].x};
            f32x2 sh23 = {D[c].y, D[c].z};
            f32x2 pdd01 = pk_fma(d01, cneg1, p01);   // d[f-1]-d[f]
            f32x2 pdd23 = pk_fma(d23, cneg1, p23);
            f32x2 tdd01 = pk_fma(d01, cneg1, sh01);  // d[t-1]-d[t]
            f32x2 tdd23 = pk_fma(d23, cneg1, sh23);
            if (c == 3) {  // lanes>=8: d==0 already, but tdd.x would leak dm1
                tdd01 = pk_mul(tdd01, m2);
                tdd23 = pk_mul(tdd23, m2);
            }
            aw_acc(d01,  ipA, ipB, cinv, cmag, cnmag, cn2pi);
            aw_acc(d23,  ipA, ipB, cinv, cmag, cnmag, cn2pi);
            aw_acc(pdd01, gdA, gdB, cinv, cmag, cnmag, cn2pi);
            aw_acc(pdd23, gdA, gdB, cinv, cmag, cnmag, cn2pi);
            aw_acc(tdd01, ptA, ptB, cinv, cmag, cnmag, cn2pi);
            aw_acc(tdd23, ptA, ptB, cinv, cmag, cnmag, cn2pi);
        }
    };

    float4 D0[4], D1[4];
    float dm0, dm1v;

    if (len == 1) {
        loadj(0, 0);               // row f0-1 (=511)
        loadj(1, 1);               // row f0   (=512)
        diff(0, D0, dm0);
        diff(1, D1, dm1v);
        acc(D1, dm1v, D0);
    } else {
        // Prologue: rows j=0,1,2 in flight.
        loadj(0, 0);
        loadj(1, 1);
        loadj(2, 2);
        diff(0, D0, dm0);          // row f0-1 -> Dprev
        if (f0 == 0) {
            #pragma unroll
            for (int c = 0; c < 4; ++c) D0[c] = make_float4(0.f, 0.f, 0.f, 0.f);
        }
        // Steady state: consuming row j keeps rows j+1, j+2 in flight.
        #pragma unroll
        for (int i = 0; i < FCH; i += 2) {
            if (i + 3 <= FCH) loadj((i + 3) % 3, i + 3);
            diff((i + 1) % 3, D1, dm1v);   // row f0+i
            acc(D1, dm1v, D0);
            if (i + 4 <= FCH) loadj((i + 4) % 3, i + 4);
            diff((i + 2) % 3, D0, dm0);    // row f0+i+1
            acc(D0, dm0, D1);
        }
    }

    // Wave reduction, then cross-wave via LDS.
    float s_ip = ipA + ipB, s_gd = gdA + gdB, s_ptd = ptA + ptB;
    #pragma unroll
    for (int off = 32; off > 0; off >>= 1) {
        s_ip  += __shfl_down(s_ip, off);
        s_gd  += __shfl_down(s_gd, off);
        s_ptd += __shfl_down(s_ptd, off);
    }
    __shared__ float sm[3][WPB];
    if (lane == 0) { sm[0][widx] = s_ip; sm[1][widx] = s_gd; sm[2][widx] = s_ptd; }
    __syncthreads();

    if (use_atomic) {
        if (threadIdx.x == 0) {
            float a = 0.f, bb = 0.f, c = 0.f;
            #pragma unroll
            for (int w = 0; w < WPB; ++w) { a += sm[0][w]; bb += sm[1][w]; c += sm[2][w]; }
            const float invN = (float)(1.0 / (double)NTOT);
            atomicAdd(out + 0, a * invN);
            atomicAdd(out + 1, bb * invN);
            atomicAdd(out + 2, c * invN);
        }
        return;
    }

    if (threadIdx.x == 0) {
        float a = 0.f, bb = 0.f, c = 0.f;
        #pragma unroll
        for (int w = 0; w < WPB; ++w) { a += sm[0][w]; bb += sm[1][w]; c += sm[2][w]; }
        partials[0 * NBLK + blockIdx.x] = a;
        partials[1 * NBLK + blockIdx.x] = bb;
        partials[2 * NBLK + blockIdx.x] = c;
    }

    // Last-arriving block reduces all partials (deterministic order).
    __shared__ int lastBlk;
    if (threadIdx.x == 0) {
        __threadfence();
        unsigned old = __hip_atomic_fetch_add(counter, 1u, __ATOMIC_ACQ_REL,
                                              __HIP_MEMORY_SCOPE_AGENT);
        lastBlk = (old == (unsigned)(NBLK - 1));
    }
    __syncthreads();
    if (lastBlk && widx == 0) {
        const float invN = (float)(1.0 / (double)NTOT);
        #pragma unroll
        for (int c = 0; c < 3; ++c) {
            float s = 0.f;
            for (int i = lane; i < NBLK; i += 64)
                s += __hip_atomic_load(&partials[c * NBLK + i],
                                       __ATOMIC_RELAXED,
                                       __HIP_MEMORY_SCOPE_AGENT);
            #pragma unroll
            for (int off = 32; off > 0; off >>= 1)
                s += __shfl_down(s, off);
            if (lane == 0) out[c] = s * invN;
        }
    }
}

__global__ void zero3(float* out) {
    if (threadIdx.x < 3) out[threadIdx.x] = 0.f;
}

extern "C" void kernel_launch(void* const* d_in, const int* in_sizes, int n_in,
                              void* d_out, int out_size, void* d_ws, size_t ws_size,
                              hipStream_t stream) {
    const float* pr = (const float*)d_in[0];
    const float* pg = (const float*)d_in[1];
    float* out = (float*)d_out;

    const size_t need = (size_t)NBLK * 3 * sizeof(float) + sizeof(unsigned);
    if (ws_size >= need) {
        float* partials = (float*)d_ws;
        unsigned* counter = (unsigned*)((char*)d_ws
                          + (size_t)NBLK * 3 * sizeof(float));
        hipMemsetAsync(counter, 0, sizeof(unsigned), stream);
        phase_main<<<NBLK, BLK, 0, stream>>>(pr, pg, partials, counter, out, 0);
    } else {
        zero3<<<1, 64, 0, stream>>>(out);
        phase_main<<<NBLK, BLK, 0, stream>>>(pr, pg, nullptr, nullptr, out, 1);
    }
}